// Round 6
// baseline (1618.127 us; speedup 1.0000x reference)
//
#include <hip/hip_runtime.h>
#include <math.h>

#define N_NODES 100000
#define N_EDGES 1200000
#define N_GRAPHS 16
#define CH 64
#define HEADS 4
#define GL 6
#define IN_DIM 261
#define GDIM 24
#define LIN 32
#define LL 3
#define EPSN 1e-5f
#define NBUK 1024          // dst>>7 -> 782 used
#define NPART 16           // moments partials

typedef unsigned short u16;
typedef __attribute__((ext_vector_type(8))) short bf16x8;
typedef __attribute__((ext_vector_type(4))) float f32x4;

__device__ __forceinline__ u16 f2bf(float f) {
  unsigned u = __float_as_uint(f);
  u = (u + 0x7FFFu + ((u >> 16) & 1u)) >> 16;
  return (u16)u;
}
__device__ __forceinline__ float bf2f(u16 v) {
  return __uint_as_float(((unsigned)v) << 16);
}

__device__ __forceinline__ float gelu_exact(float x) {
  return 0.5f * x * (1.0f + erff(x * 0.70710678118654752440f));
}

__device__ __forceinline__ float ln32(float x, float w, float b) {
  float m = x;
  m += __shfl_xor(m, 1); m += __shfl_xor(m, 2); m += __shfl_xor(m, 4);
  m += __shfl_xor(m, 8); m += __shfl_xor(m, 16);
  m *= (1.0f / 32.0f);
  float d = x - m;
  float v = d * d;
  v += __shfl_xor(v, 1); v += __shfl_xor(v, 2); v += __shfl_xor(v, 4);
  v += __shfl_xor(v, 8); v += __shfl_xor(v, 16);
  v *= (1.0f / 32.0f);
  return d * rsqrtf(v + EPSN) * w + b;
}

// ---------------- setup: CSR build (bucketed two-pass sort by dst) ----------------
__global__ void k_hist(const int* __restrict__ dst, int* __restrict__ deg,
                       int* __restrict__ bhist) {
  int e = blockIdx.x * 256 + threadIdx.x;
  if (e < N_EDGES) {
    int d = dst[e];
    atomicAdd(&deg[d], 1);
    atomicAdd(&bhist[d >> 7], 1);
  }
}

__global__ void k_block_sums(const int* __restrict__ deg, int* __restrict__ bsum) {
  __shared__ int sh[256];
  int i = blockIdx.x * 256 + threadIdx.x;
  sh[threadIdx.x] = (i < N_NODES) ? deg[i] : 0;
  __syncthreads();
  for (int s = 128; s > 0; s >>= 1) {
    if (threadIdx.x < s) sh[threadIdx.x] += sh[threadIdx.x + s];
    __syncthreads();
  }
  if (threadIdx.x == 0) bsum[blockIdx.x] = sh[0];
}

__global__ void k_scan_bsums(int* __restrict__ bsum, int nb, int* __restrict__ off) {
  __shared__ int sh[512];
  int i = threadIdx.x;
  int v = (i < nb) ? bsum[i] : 0;
  sh[i] = v;
  __syncthreads();
  for (int s = 1; s < 512; s <<= 1) {
    int t = (i >= s) ? sh[i - s] : 0;
    __syncthreads();
    sh[i] += t;
    __syncthreads();
  }
  if (i < nb) bsum[i] = sh[i] - v;
  if (i == nb - 1) off[N_NODES] = sh[i];
}

__global__ void k_scan_final(const int* __restrict__ deg, const int* __restrict__ bsum,
                             int* __restrict__ off, int* __restrict__ cur) {
  __shared__ int sh[256];
  int i = blockIdx.x * 256 + threadIdx.x;
  int v = (i < N_NODES) ? deg[i] : 0;
  sh[threadIdx.x] = v;
  __syncthreads();
  for (int s = 1; s < 256; s <<= 1) {
    int t = (threadIdx.x >= s) ? sh[threadIdx.x - s] : 0;
    __syncthreads();
    sh[threadIdx.x] += t;
    __syncthreads();
  }
  if (i < N_NODES) {
    int ex = bsum[blockIdx.x] + sh[threadIdx.x] - v;
    off[i] = ex;
    cur[i] = ex;
  }
}

__global__ void k_scan_buckets(const int* __restrict__ bhist, int* __restrict__ bcur) {
  __shared__ int sh[NBUK];
  int i = threadIdx.x;
  int v = bhist[i];
  sh[i] = v;
  __syncthreads();
  for (int s = 1; s < NBUK; s <<= 1) {
    int t = (i >= s) ? sh[i - s] : 0;
    __syncthreads();
    sh[i] += t;
    __syncthreads();
  }
  bcur[i] = sh[i] - v;   // exclusive prefix = bucket cursor start
}

__global__ void k_bucket_scatter(const int* __restrict__ src, const int* __restrict__ dst,
                                 int* __restrict__ bcur, int2* __restrict__ ebuf) {
  int e = blockIdx.x * 256 + threadIdx.x;
  if (e < N_EDGES) {
    int d = dst[e];
    int p = atomicAdd(&bcur[d >> 7], 1);
    ebuf[p] = make_int2(src[e], d);
  }
}

__global__ void k_final_scatter(const int2* __restrict__ ebuf, int* __restrict__ cur,
                                int* __restrict__ ssrc) {
  int e = blockIdx.x * 256 + threadIdx.x;
  if (e < N_EDGES) {
    int2 pr = ebuf[e];
    int p = atomicAdd(&cur[pr.y], 1);
    ssrc[p] = pr.x;
  }
}

__global__ void k_graph_starts(const int* __restrict__ batch, int* __restrict__ gstart) {
  int g = threadIdx.x;
  if (g > N_GRAPHS) return;
  int lo = 0, hi = N_NODES;
  while (lo < hi) {
    int mid = (lo + hi) >> 1;
    if (batch[mid] < g) lo = mid + 1; else hi = mid;
  }
  gstart[g] = lo;
}

// ---------------- weight prep: fp32 -> bf16 B-fragment swizzle ----------------
#define W0S_ELEMS (4 * 9 * 64 * 8)
#define WGS_ELEMS (4 * 2 * 64 * 8)
__global__ void k_prep_w(const float* __restrict__ W0, const float* __restrict__ Wg,
                         u16* __restrict__ W0s, u16* __restrict__ Wgs) {
  int idx = blockIdx.x * 256 + threadIdx.x;
  if (idx < W0S_ELEMS) {
    int i = idx & 7, lane = (idx >> 3) & 63, ks = (idx >> 9) % 9, cb = idx / (9 * 512);
    int k = ks * 32 + (lane >> 4) * 8 + i, c = cb * 16 + (lane & 15);
    W0s[idx] = f2bf(k < IN_DIM ? W0[k * 64 + c] : 0.f);
  } else if (idx < W0S_ELEMS + GL * WGS_ELEMS) {
    int j = idx - W0S_ELEMS;
    int l = j / WGS_ELEMS, p = j % WGS_ELEMS;
    int i = p & 7, lane = (p >> 3) & 63, ks = (p >> 9) & 1, cb = p / (2 * 512);
    int k = ks * 32 + (lane >> 4) * 8 + i, c = cb * 16 + (lane & 15);
    Wgs[j] = f2bf(Wg[(size_t)l * 4096 + k * 64 + c]);
  }
}

// ---------------- per-layer: MFMA GEMM (T = X @ W, bf16) + attention logits ----------------
template <int KS, bool F32IN>
__global__ __launch_bounds__(256) void k_gemm_mfma(
    const void* __restrict__ Xin, const u16* __restrict__ Wswz,
    const float* __restrict__ a_src, const float* __restrict__ a_dst,
    u16* __restrict__ Tb, float* __restrict__ ES, float* __restrict__ ED) {
  const int lane = threadIdx.x & 63;
  const int wid = (blockIdx.x << 2) + (threadIdx.x >> 6);
  const int NT = N_NODES / 16;
  if (wid >= NT) return;
  const int grp = lane >> 4, n16 = lane & 15;
  float as_l[4], ad_l[4];
  #pragma unroll
  for (int cb = 0; cb < 4; ++cb) {
    as_l[cb] = a_src[cb * 16 + n16];
    ad_l[cb] = a_dst[cb * 16 + n16];
  }
  const long r0 = (long)wid * 16;

  bf16x8 afr[KS];
  if constexpr (!F32IN) {
    const u16* xrow = (const u16*)Xin + (r0 + n16) * (KS * 32) + grp * 8;
    #pragma unroll
    for (int ks = 0; ks < KS; ++ks) afr[ks] = *(const bf16x8*)(xrow + ks * 32);
  } else {
    const float* xr = (const float*)Xin + (r0 + n16) * (size_t)IN_DIM;
    #pragma unroll
    for (int ks = 0; ks < KS; ++ks) {
      bf16x8 a;
      #pragma unroll
      for (int i = 0; i < 8; ++i) {
        int k = ks * 32 + grp * 8 + i;
        float v = (k < IN_DIM) ? xr[k] : 0.f;
        a[i] = (short)f2bf(v);
      }
      afr[ks] = a;
    }
  }

  f32x4 acc[4];
  #pragma unroll
  for (int cb = 0; cb < 4; ++cb) {
    f32x4 a = {0.f, 0.f, 0.f, 0.f};
    #pragma unroll
    for (int ks = 0; ks < KS; ++ks) {
      bf16x8 b = *(const bf16x8*)(Wswz + ((size_t)(cb * KS + ks) * 64 + lane) * 8);
      a = __builtin_amdgcn_mfma_f32_16x16x32_bf16(afr[ks], b, a, 0, 0, 0);
    }
    acc[cb] = a;
  }

  #pragma unroll
  for (int r = 0; r < 4; ++r) {
    const long row = r0 + grp * 4 + r;
    #pragma unroll
    for (int cb = 0; cb < 4; ++cb) {
      float v = acc[cb][r];
      Tb[row * 64 + cb * 16 + n16] = f2bf(v);
      float s = v * as_l[cb];
      float d = v * ad_l[cb];
      s += __shfl_xor(s, 1); s += __shfl_xor(s, 2); s += __shfl_xor(s, 4); s += __shfl_xor(s, 8);
      d += __shfl_xor(d, 1); d += __shfl_xor(d, 2); d += __shfl_xor(d, 4); d += __shfl_xor(d, 8);
      if (n16 == 0) {
        ES[row * 4 + cb] = s;
        ED[row * 4 + cb] = d;
      }
    }
  }
}

// ---------------- per-layer: edge softmax + aggregate (wave per node) ----------------
__global__ __launch_bounds__(256) void k_edge_agg(
    const u16* __restrict__ Tb, const float* __restrict__ ES, const float* __restrict__ ED,
    const int* __restrict__ off, const int* __restrict__ ssrc,
    const float* __restrict__ bias, float* __restrict__ F) {
  const int lane = threadIdx.x & 63;
  const int n = blockIdx.x * 4 + (threadIdx.x >> 6);
  if (n >= N_NODES) return;
  const int e0 = off[n];
  const int ec = off[n + 1] - e0;
  const int hd = lane & 3;
  const int qh = lane >> 4;
  const float ed_h = ED[n * 4 + hd];
  float x0 = ES[n * 4 + hd] + ed_h;
  x0 = fmaxf(x0, 0.2f * x0);
  float m_run = x0;
  float s_run = 1.0f;
  const u16* Tl = Tb + lane;
  float acc = bf2f(Tl[(long)n * 64]);
  for (int base = 0; base < ec; base += 16) {
    const int eidx = base + (lane >> 2);
    const bool valid = eidx < ec;
    const int sv = valid ? ssrc[e0 + eidx] : n;
    float v = ES[sv * 4 + hd] + ed_h;
    float logit = valid ? fmaxf(v, 0.2f * v) : -1e30f;
    float cm = logit;
    cm = fmaxf(cm, __shfl_xor(cm, 4));
    cm = fmaxf(cm, __shfl_xor(cm, 8));
    cm = fmaxf(cm, __shfl_xor(cm, 16));
    cm = fmaxf(cm, __shfl_xor(cm, 32));
    const float new_m = fmaxf(m_run, cm);
    const float scale = __expf(m_run - new_m);
    const float p = valid ? __expf(logit - new_m) : 0.f;
    float ps = p;
    ps += __shfl_xor(ps, 4); ps += __shfl_xor(ps, 8);
    ps += __shfl_xor(ps, 16); ps += __shfl_xor(ps, 32);
    s_run = fmaf(s_run, scale, ps);
    m_run = new_m;
    acc *= __shfl(scale, qh);
    int rows[16];
    float al[16], tv[16];
    #pragma unroll
    for (int e = 0; e < 16; ++e) rows[e] = __shfl(sv, e << 2);
    #pragma unroll
    for (int e = 0; e < 16; ++e) al[e] = __shfl(p, (e << 2) | qh);
    #pragma unroll
    for (int e = 0; e < 16; ++e) tv[e] = bf2f(Tl[(long)rows[e] * 64]);
    #pragma unroll
    for (int e = 0; e < 16; ++e) acc = fmaf(al[e], tv[e], acc);
  }
  const float s_q = __shfl(s_run, qh);
  const float o = acc / (s_q + 1e-16f) + bias[lane];
  F[(long)n * 64 + lane] = gelu_exact(o);
}

// ---------------- GraphNorm: partial moments ----------------
__global__ void k_graph_moments(const float* __restrict__ F, const int* __restrict__ gstart,
                                float* __restrict__ SP, float* __restrict__ SQP) {
  const int g = blockIdx.x;
  const int s0 = gstart[g];
  const int rows = gstart[g + 1] - s0;
  const int lane = threadIdx.x & 63;
  const int w = threadIdx.x >> 6;
  float sum = 0.f, sq = 0.f;
  for (int r = blockIdx.y * 4 + w; r < rows; r += gridDim.y * 4) {
    float v = F[(long)(s0 + r) * 64 + lane];
    sum += v;
    sq = fmaf(v, v, sq);
  }
  __shared__ float ls[4][64];
  __shared__ float lq[4][64];
  ls[w][lane] = sum;
  lq[w][lane] = sq;
  __syncthreads();
  if (w == 0) {
    float a = ls[0][lane] + ls[1][lane] + ls[2][lane] + ls[3][lane];
    float b = lq[0][lane] + lq[1][lane] + lq[2][lane] + lq[3][lane];
    SP[(blockIdx.y * N_GRAPHS + g) * 64 + lane] = a;
    SQP[(blockIdx.y * N_GRAPHS + g) * 64 + lane] = b;
  }
}

__global__ void k_graph_stats(const float* __restrict__ SP, const float* __restrict__ SQP,
                              const int* __restrict__ gstart, const float* __restrict__ ms,
                              float* __restrict__ MM, float* __restrict__ IS) {
  const int i = threadIdx.x;
  const int g = i >> 6, c = i & 63;
  float s = 0.f, q = 0.f;
  #pragma unroll
  for (int b = 0; b < NPART; ++b) {
    s += SP[(b * N_GRAPHS + g) * 64 + c];
    q += SQP[(b * N_GRAPHS + g) * 64 + c];
  }
  const float cnt = fmaxf((float)(gstart[g + 1] - gstart[g]), 1.0f);
  const float mean = s / cnt;
  const float mm = mean * ms[c];
  float var = q / cnt - 2.f * mm * mean + mm * mm;
  MM[i] = mm;
  IS[i] = rsqrtf(fmaxf(var, 0.f) + EPSN);
}

__global__ void k_norm_res(const float* __restrict__ F, const int* __restrict__ batch,
                           const float* __restrict__ MM, const float* __restrict__ IS,
                           const float* __restrict__ w, const float* __restrict__ b,
                           float* __restrict__ X, u16* __restrict__ Xb, int residual) {
  const long i4 = (long)blockIdx.x * 256 + threadIdx.x;
  const int n = (int)(i4 >> 4);
  const int c4 = (int)(i4 & 15) << 2;
  const int g = batch[n];
  float4 f = *(const float4*)(F + i4 * 4);
  float4 mm = *(const float4*)(MM + g * 64 + c4);
  float4 is = *(const float4*)(IS + g * 64 + c4);
  float4 wv = *(const float4*)(w + c4);
  float4 bv = *(const float4*)(b + c4);
  float4 y;
  y.x = fmaf(wv.x * (f.x - mm.x), is.x, bv.x);
  y.y = fmaf(wv.y * (f.y - mm.y), is.y, bv.y);
  y.z = fmaf(wv.z * (f.z - mm.z), is.z, bv.z);
  y.w = fmaf(wv.w * (f.w - mm.w), is.w, bv.w);
  float4* xp = (float4*)(X + i4 * 4);
  if (residual) {
    float4 xo = *xp;
    y.x += xo.x; y.y += xo.y; y.z += xo.z; y.w += xo.w;
  }
  *xp = y;
  union { u16 s[4]; unsigned long long ll; } pk;
  pk.s[0] = f2bf(y.x); pk.s[1] = f2bf(y.y); pk.s[2] = f2bf(y.z); pk.s[3] = f2bf(y.w);
  *(unsigned long long*)(Xb + i4 * 4) = pk.ll;
}

// ---------------- pooled MLP head (one block) ----------------
__global__ __launch_bounds__(512) void k_mlp(
    const float* __restrict__ SP, const int* __restrict__ gstart, const float* __restrict__ gf,
    const float* __restrict__ W0, const float* __restrict__ b0,
    const float* __restrict__ lw0, const float* __restrict__ lb0,
    const float* __restrict__ Wg, const float* __restrict__ bg,
    const float* __restrict__ lwg, const float* __restrict__ lbg,
    const float* __restrict__ hW, const float* __restrict__ hb,
    float* __restrict__ out) {
  __shared__ float P[16][88];
  __shared__ float Z[16][32];
  const int tid = threadIdx.x;
  for (int i = tid; i < 16 * 88; i += 512) {
    int g = i / 88, c = i - g * 88;
    float v;
    if (c < 64) {
      float s = 0.f;
      #pragma unroll
      for (int b = 0; b < NPART; ++b) s += SP[(b * N_GRAPHS + g) * 64 + c];
      float cnt = fmaxf((float)(gstart[g + 1] - gstart[g]), 1.0f);
      v = s / cnt;
    } else {
      v = gf[g * GDIM + (c - 64)];
    }
    P[g][c] = v;
  }
  __syncthreads();
  const int g = tid >> 5, c = tid & 31;
  float acc = b0[c];
  for (int k = 0; k < 88; ++k) acc = fmaf(P[g][k], W0[k * 32 + c], acc);
  float z = ln32(gelu_exact(acc), lw0[c], lb0[c]);
  for (int l = 0; l < LL; ++l) {
    Z[g][c] = z;
    __syncthreads();
    float a2 = bg[l * 32 + c];
    const float* Wl = Wg + l * 32 * 32;
    for (int k = 0; k < 32; ++k) a2 = fmaf(Z[g][k], Wl[k * 32 + c], a2);
    __syncthreads();
    z = ln32(gelu_exact(a2), lwg[l * 32 + c], lbg[l * 32 + c]) + z;
  }
  Z[g][c] = z * hW[c];
  __syncthreads();
  if (c == 0) {
    float s = 0.f;
    for (int k = 0; k < 32; ++k) s += Z[g][k];
    out[g] = s + hb[0];
  }
}

extern "C" void kernel_launch(void* const* d_in, const int* in_sizes, int n_in,
                              void* d_out, int out_size, void* d_ws, size_t ws_size,
                              hipStream_t stream) {
  const float* x   = (const float*)d_in[0];
  const int*   ei  = (const int*)d_in[1];
  const int* batch = (const int*)d_in[2];
  const float* gf  = (const float*)d_in[3];
  const float* W0  = (const float*)d_in[4];
  const float* as0 = (const float*)d_in[5];
  const float* ad0 = (const float*)d_in[6];
  const float* b0  = (const float*)d_in[7];
  const float* gw0 = (const float*)d_in[8];
  const float* gb0 = (const float*)d_in[9];
  const float* gm0 = (const float*)d_in[10];
  const float* Wg  = (const float*)d_in[11];
  const float* asg = (const float*)d_in[12];
  const float* adg = (const float*)d_in[13];
  const float* bg  = (const float*)d_in[14];
  const float* gwg = (const float*)d_in[15];
  const float* gbg = (const float*)d_in[16];
  const float* gmg = (const float*)d_in[17];
  const float* mW0 = (const float*)d_in[18];
  const float* mb0 = (const float*)d_in[19];
  const float* lw0 = (const float*)d_in[20];
  const float* lb0 = (const float*)d_in[21];
  const float* mWg = (const float*)d_in[22];
  const float* mbg = (const float*)d_in[23];
  const float* lwg = (const float*)d_in[24];
  const float* lbg = (const float*)d_in[25];
  const float* hW  = (const float*)d_in[26];
  const float* hb  = (const float*)d_in[27];
  float* out = (float*)d_out;
  const int* src = ei;
  const int* dst = ei + N_EDGES;

  char* p = (char*)d_ws;
  auto alloc = [&](size_t bytes) {
    char* r = p;
    p += (bytes + 255) & ~(size_t)255;
    return (void*)r;
  };
  float* X   = (float*)alloc((size_t)N_NODES * 64 * 4);
  float* F   = (float*)alloc((size_t)N_NODES * 64 * 4);
  u16*   Xb  = (u16*)alloc((size_t)N_NODES * 64 * 2);
  u16*   Tb  = (u16*)alloc((size_t)N_NODES * 64 * 2);
  float* ES  = (float*)alloc((size_t)N_NODES * 4 * 4);
  float* ED  = (float*)alloc((size_t)N_NODES * 4 * 4);
  int* ssrc  = (int*)alloc((size_t)N_EDGES * 4);
  int2* ebuf = (int2*)alloc((size_t)N_EDGES * 8);
  int* deg   = (int*)alloc((size_t)N_NODES * 4);
  int* off   = (int*)alloc((size_t)(N_NODES + 1) * 4);
  int* cur   = (int*)alloc((size_t)N_NODES * 4);
  int* bsum  = (int*)alloc(4096);
  int* bhist = (int*)alloc(NBUK * 4);
  int* bcur  = (int*)alloc(NBUK * 4);
  int* gstart = (int*)alloc((N_GRAPHS + 1) * 4);
  u16* W0s   = (u16*)alloc((size_t)W0S_ELEMS * 2);
  u16* Wgs   = (u16*)alloc((size_t)GL * WGS_ELEMS * 2);
  float* SP  = (float*)alloc(NPART * N_GRAPHS * 64 * 4);
  float* SQP = (float*)alloc(NPART * N_GRAPHS * 64 * 4);
  float* MM  = (float*)alloc(N_GRAPHS * 64 * 4);
  float* IS  = (float*)alloc(N_GRAPHS * 64 * 4);
  (void)ws_size; (void)in_sizes; (void)n_in; (void)out_size;

  const int NB = (N_NODES + 255) / 256;
  const int EB = (N_EDGES + 255) / 256;
  hipMemsetAsync(deg, 0, (size_t)N_NODES * 4, stream);
  hipMemsetAsync(bhist, 0, NBUK * 4, stream);
  k_hist<<<EB, 256, 0, stream>>>(dst, deg, bhist);
  k_block_sums<<<NB, 256, 0, stream>>>(deg, bsum);
  k_scan_bsums<<<1, 512, 0, stream>>>(bsum, NB, off);
  k_scan_final<<<NB, 256, 0, stream>>>(deg, bsum, off, cur);
  k_scan_buckets<<<1, NBUK, 0, stream>>>(bhist, bcur);
  k_bucket_scatter<<<EB, 256, 0, stream>>>(src, dst, bcur, ebuf);
  k_final_scatter<<<EB, 256, 0, stream>>>(ebuf, cur, ssrc);
  k_graph_starts<<<1, 32, 0, stream>>>(batch, gstart);
  k_prep_w<<<(W0S_ELEMS + GL * WGS_ELEMS + 255) / 256, 256, 0, stream>>>(W0, Wg, W0s, Wgs);

  const int GG = (N_NODES / 16 + 3) / 4;
  for (int l = 0; l < 1 + GL; ++l) {
    const float* asl = (l == 0) ? as0 : (asg + (size_t)(l - 1) * 64);
    const float* adl = (l == 0) ? ad0 : (adg + (size_t)(l - 1) * 64);
    const float* bl  = (l == 0) ? b0  : (bg  + (size_t)(l - 1) * 64);
    const float* gwl = (l == 0) ? gw0 : (gwg + (size_t)(l - 1) * 64);
    const float* gbl = (l == 0) ? gb0 : (gbg + (size_t)(l - 1) * 64);
    const float* gml = (l == 0) ? gm0 : (gmg + (size_t)(l - 1) * 64);
    if (l == 0)
      k_gemm_mfma<9, true><<<GG, 256, 0, stream>>>(x, W0s, asl, adl, Tb, ES, ED);
    else
      k_gemm_mfma<2, false><<<GG, 256, 0, stream>>>(Xb, Wgs + (size_t)(l - 1) * WGS_ELEMS,
                                                    asl, adl, Tb, ES, ED);
    k_edge_agg<<<N_NODES / 4, 256, 0, stream>>>(Tb, ES, ED, off, ssrc, bl, F);
    k_graph_moments<<<dim3(N_GRAPHS, NPART), 256, 0, stream>>>(F, gstart, SP, SQP);
    k_graph_stats<<<1, 1024, 0, stream>>>(SP, SQP, gstart, gml, MM, IS);
    k_norm_res<<<(N_NODES * 64) / 1024, 256, 0, stream>>>(F, batch, MM, IS, gwl, gbl, X, Xb, l > 0);
  }

  k_graph_moments<<<dim3(N_GRAPHS, NPART), 256, 0, stream>>>(X, gstart, SP, SQP);
  k_mlp<<<1, 512, 0, stream>>>(SP, gstart, gf, mW0, mb0, lw0, lb0,
                               mWg, mbg, lwg, lbg, hW, hb, out);
}

// Round 7
// 989.338 us; speedup vs baseline: 1.6356x; 1.6356x over previous
//
#include <hip/hip_runtime.h>
#include <math.h>

#define N_NODES 100000
#define N_EDGES 1200000
#define N_GRAPHS 16
#define CH 64
#define HEADS 4
#define GL 6
#define IN_DIM 261
#define GDIM 24
#define LIN 32
#define LL 3
#define EPSN 1e-5f
#define NPART 16           // moments partials
#define RNG (N_NODES / 8)  // 12500 nodes per dst-range

typedef unsigned short u16;
typedef __attribute__((ext_vector_type(8))) short bf16x8;
typedef __attribute__((ext_vector_type(4))) float f32x4;

__device__ __forceinline__ u16 f2bf(float f) {
  unsigned u = __float_as_uint(f);
  u = (u + 0x7FFFu + ((u >> 16) & 1u)) >> 16;
  return (u16)u;
}
__device__ __forceinline__ float bf2f(u16 v) {
  return __uint_as_float(((unsigned)v) << 16);
}

__device__ __forceinline__ float gelu_exact(float x) {
  return 0.5f * x * (1.0f + erff(x * 0.70710678118654752440f));
}

__device__ __forceinline__ float ln32(float x, float w, float b) {
  float m = x;
  m += __shfl_xor(m, 1); m += __shfl_xor(m, 2); m += __shfl_xor(m, 4);
  m += __shfl_xor(m, 8); m += __shfl_xor(m, 16);
  m *= (1.0f / 32.0f);
  float d = x - m;
  float v = d * d;
  v += __shfl_xor(v, 1); v += __shfl_xor(v, 2); v += __shfl_xor(v, 4);
  v += __shfl_xor(v, 8); v += __shfl_xor(v, 16);
  v *= (1.0f / 32.0f);
  return d * rsqrtf(v + EPSN) * w + b;
}

// ---------------- setup: CSR build, dst-range partitioned ----------------
// range = blockIdx.x & 7 (bid%8 ~ XCD heuristic): atomics + stores stay XCD-local.
__global__ void k_count_part(const int* __restrict__ dst, int* __restrict__ deg) {
  const int range = blockIdx.x & 7;
  const int sub = blockIdx.x >> 3;            // 0..255
  const int lo = range * RNG, hi = lo + RNG;
  for (int e = sub * 256 + threadIdx.x; e < N_EDGES; e += 256 * 256) {
    int d = dst[e];
    if (d >= lo && d < hi) atomicAdd(&deg[d], 1);
  }
}

__global__ void k_scatter_part(const int* __restrict__ src, const int* __restrict__ dst,
                               int* __restrict__ cur, int* __restrict__ ssrc) {
  const int range = blockIdx.x & 7;
  const int sub = blockIdx.x >> 3;
  const int lo = range * RNG, hi = lo + RNG;
  for (int e = sub * 256 + threadIdx.x; e < N_EDGES; e += 256 * 256) {
    int d = dst[e];
    if (d >= lo && d < hi) {
      int p = atomicAdd(&cur[d], 1);
      ssrc[p] = src[e];
    }
  }
}

__global__ void k_block_sums(const int* __restrict__ deg, int* __restrict__ bsum) {
  __shared__ int sh[256];
  int i = blockIdx.x * 256 + threadIdx.x;
  sh[threadIdx.x] = (i < N_NODES) ? deg[i] : 0;
  __syncthreads();
  for (int s = 128; s > 0; s >>= 1) {
    if (threadIdx.x < s) sh[threadIdx.x] += sh[threadIdx.x + s];
    __syncthreads();
  }
  if (threadIdx.x == 0) bsum[blockIdx.x] = sh[0];
}

__global__ void k_scan_bsums(int* __restrict__ bsum, int nb, int* __restrict__ off) {
  __shared__ int sh[512];
  int i = threadIdx.x;
  int v = (i < nb) ? bsum[i] : 0;
  sh[i] = v;
  __syncthreads();
  for (int s = 1; s < 512; s <<= 1) {
    int t = (i >= s) ? sh[i - s] : 0;
    __syncthreads();
    sh[i] += t;
    __syncthreads();
  }
  if (i < nb) bsum[i] = sh[i] - v;
  if (i == nb - 1) off[N_NODES] = sh[i];
}

__global__ void k_scan_final(const int* __restrict__ deg, const int* __restrict__ bsum,
                             int* __restrict__ off, int* __restrict__ cur) {
  __shared__ int sh[256];
  int i = blockIdx.x * 256 + threadIdx.x;
  int v = (i < N_NODES) ? deg[i] : 0;
  sh[threadIdx.x] = v;
  __syncthreads();
  for (int s = 1; s < 256; s <<= 1) {
    int t = (threadIdx.x >= s) ? sh[threadIdx.x - s] : 0;
    __syncthreads();
    sh[threadIdx.x] += t;
    __syncthreads();
  }
  if (i < N_NODES) {
    int ex = bsum[blockIdx.x] + sh[threadIdx.x] - v;
    off[i] = ex;
    cur[i] = ex;
  }
}

__global__ void k_graph_starts(const int* __restrict__ batch, int* __restrict__ gstart) {
  int g = threadIdx.x;
  if (g > N_GRAPHS) return;
  int lo = 0, hi = N_NODES;
  while (lo < hi) {
    int mid = (lo + hi) >> 1;
    if (batch[mid] < g) lo = mid + 1; else hi = mid;
  }
  gstart[g] = lo;
}

// ---------------- weight prep: fp32 -> bf16 B-fragment swizzle ----------------
#define W0S_ELEMS (4 * 9 * 64 * 8)
#define WGS_ELEMS (4 * 2 * 64 * 8)
__global__ void k_prep_w(const float* __restrict__ W0, const float* __restrict__ Wg,
                         u16* __restrict__ W0s, u16* __restrict__ Wgs) {
  int idx = blockIdx.x * 256 + threadIdx.x;
  if (idx < W0S_ELEMS) {
    int i = idx & 7, lane = (idx >> 3) & 63, ks = (idx >> 9) % 9, cb = idx / (9 * 512);
    int k = ks * 32 + (lane >> 4) * 8 + i, c = cb * 16 + (lane & 15);
    W0s[idx] = f2bf(k < IN_DIM ? W0[k * 64 + c] : 0.f);
  } else if (idx < W0S_ELEMS + GL * WGS_ELEMS) {
    int j = idx - W0S_ELEMS;
    int l = j / WGS_ELEMS, p = j % WGS_ELEMS;
    int i = p & 7, lane = (p >> 3) & 63, ks = (p >> 9) & 1, cb = p / (2 * 512);
    int k = ks * 32 + (lane >> 4) * 8 + i, c = cb * 16 + (lane & 15);
    Wgs[j] = f2bf(Wg[(size_t)l * 4096 + k * 64 + c]);
  }
}

// ---------------- per-layer: MFMA GEMM (T = X @ W, bf16) + attention logits ----------------
template <int KS, bool F32IN>
__global__ __launch_bounds__(256) void k_gemm_mfma(
    const void* __restrict__ Xin, const u16* __restrict__ Wswz,
    const float* __restrict__ a_src, const float* __restrict__ a_dst,
    u16* __restrict__ Tb, float* __restrict__ ES, float* __restrict__ ED) {
  const int lane = threadIdx.x & 63;
  const int wid = (blockIdx.x << 2) + (threadIdx.x >> 6);
  const int NT = N_NODES / 16;
  if (wid >= NT) return;
  const int grp = lane >> 4, n16 = lane & 15;
  float as_l[4], ad_l[4];
  #pragma unroll
  for (int cb = 0; cb < 4; ++cb) {
    as_l[cb] = a_src[cb * 16 + n16];
    ad_l[cb] = a_dst[cb * 16 + n16];
  }
  const long r0 = (long)wid * 16;

  bf16x8 afr[KS];
  if constexpr (!F32IN) {
    const u16* xrow = (const u16*)Xin + (r0 + n16) * (KS * 32) + grp * 8;
    #pragma unroll
    for (int ks = 0; ks < KS; ++ks) afr[ks] = *(const bf16x8*)(xrow + ks * 32);
  } else {
    const float* xr = (const float*)Xin + (r0 + n16) * (size_t)IN_DIM;
    #pragma unroll
    for (int ks = 0; ks < KS; ++ks) {
      bf16x8 a;
      #pragma unroll
      for (int i = 0; i < 8; ++i) {
        int k = ks * 32 + grp * 8 + i;
        float v = (k < IN_DIM) ? xr[k] : 0.f;
        a[i] = (short)f2bf(v);
      }
      afr[ks] = a;
    }
  }

  f32x4 acc[4];
  #pragma unroll
  for (int cb = 0; cb < 4; ++cb) {
    f32x4 a = {0.f, 0.f, 0.f, 0.f};
    #pragma unroll
    for (int ks = 0; ks < KS; ++ks) {
      bf16x8 b = *(const bf16x8*)(Wswz + ((size_t)(cb * KS + ks) * 64 + lane) * 8);
      a = __builtin_amdgcn_mfma_f32_16x16x32_bf16(afr[ks], b, a, 0, 0, 0);
    }
    acc[cb] = a;
  }

  #pragma unroll
  for (int r = 0; r < 4; ++r) {
    const long row = r0 + grp * 4 + r;
    #pragma unroll
    for (int cb = 0; cb < 4; ++cb) {
      float v = acc[cb][r];
      Tb[row * 64 + cb * 16 + n16] = f2bf(v);
      float s = v * as_l[cb];
      float d = v * ad_l[cb];
      s += __shfl_xor(s, 1); s += __shfl_xor(s, 2); s += __shfl_xor(s, 4); s += __shfl_xor(s, 8);
      d += __shfl_xor(d, 1); d += __shfl_xor(d, 2); d += __shfl_xor(d, 4); d += __shfl_xor(d, 8);
      if (n16 == 0) {
        ES[row * 4 + cb] = s;
        ED[row * 4 + cb] = d;
      }
    }
  }
}

// ---------------- per-layer: edge softmax + aggregate (wave per node) ----------------
// No running max (logits bounded, clamp 25); T gathers issued before ES chain.
__global__ __launch_bounds__(256) void k_edge_agg(
    const u16* __restrict__ Tb, const float* __restrict__ ES, const float* __restrict__ ED,
    const int* __restrict__ off, const int* __restrict__ ssrc,
    const float* __restrict__ bias, float* __restrict__ F) {
  const int lane = threadIdx.x & 63;
  const int n = blockIdx.x * 4 + (threadIdx.x >> 6);
  if (n >= N_NODES) return;
  const int e0 = off[n];
  const int ec = off[n + 1] - e0;
  const int hd = lane & 3;
  const int qh = lane >> 4;
  const u16* Tl = Tb + lane;
  const float tself = bf2f(Tl[(long)n * 64]);   // issue early
  const float ed_h = ED[n * 4 + hd];
  float x0 = ES[n * 4 + hd] + ed_h;
  x0 = fmaxf(x0, 0.2f * x0);
  const float p0 = __expf(fminf(x0, 25.f));
  float s_run = p0;                              // per-lane head hd
  float acc = __shfl(p0, qh) * tself;            // my channel's head weight
  for (int base = 0; base < ec; base += 16) {
    const int eidx = base + (lane >> 2);
    const bool valid = eidx < ec;
    const int sv = valid ? ssrc[e0 + eidx] : n;
    // T-row gathers first: overlap with ES gather below
    int rows[16];
    #pragma unroll
    for (int e = 0; e < 16; ++e) rows[e] = __shfl(sv, e << 2);
    float tv[16];
    #pragma unroll
    for (int e = 0; e < 16; ++e) tv[e] = bf2f(Tl[(long)rows[e] * 64]);
    // logits
    float v = ES[sv * 4 + hd] + ed_h;
    v = fmaxf(v, 0.2f * v);
    const float p = valid ? __expf(fminf(v, 25.f)) : 0.f;
    float ps = p;
    ps += __shfl_xor(ps, 4); ps += __shfl_xor(ps, 8);
    ps += __shfl_xor(ps, 16); ps += __shfl_xor(ps, 32);
    s_run += ps;
    #pragma unroll
    for (int e = 0; e < 16; ++e)
      acc = fmaf(__shfl(p, (e << 2) | qh), tv[e], acc);
  }
  const float s_q = __shfl(s_run, qh);
  const float o = acc / (s_q + 1e-16f) + bias[lane];
  F[(long)n * 64 + lane] = gelu_exact(o);
}

// ---------------- GraphNorm: partial moments ----------------
__global__ void k_graph_moments(const float* __restrict__ F, const int* __restrict__ gstart,
                                float* __restrict__ SP, float* __restrict__ SQP) {
  const int g = blockIdx.x;
  const int s0 = gstart[g];
  const int rows = gstart[g + 1] - s0;
  const int lane = threadIdx.x & 63;
  const int w = threadIdx.x >> 6;
  float sum = 0.f, sq = 0.f;
  for (int r = blockIdx.y * 4 + w; r < rows; r += gridDim.y * 4) {
    float v = F[(long)(s0 + r) * 64 + lane];
    sum += v;
    sq = fmaf(v, v, sq);
  }
  __shared__ float ls[4][64];
  __shared__ float lq[4][64];
  ls[w][lane] = sum;
  lq[w][lane] = sq;
  __syncthreads();
  if (w == 0) {
    float a = ls[0][lane] + ls[1][lane] + ls[2][lane] + ls[3][lane];
    float b = lq[0][lane] + lq[1][lane] + lq[2][lane] + lq[3][lane];
    SP[(blockIdx.y * N_GRAPHS + g) * 64 + lane] = a;
    SQP[(blockIdx.y * N_GRAPHS + g) * 64 + lane] = b;
  }
}

__global__ void k_graph_stats(const float* __restrict__ SP, const float* __restrict__ SQP,
                              const int* __restrict__ gstart, const float* __restrict__ ms,
                              float* __restrict__ MM, float* __restrict__ IS) {
  const int i = threadIdx.x;
  const int g = i >> 6, c = i & 63;
  float s = 0.f, q = 0.f;
  #pragma unroll
  for (int b = 0; b < NPART; ++b) {
    s += SP[(b * N_GRAPHS + g) * 64 + c];
    q += SQP[(b * N_GRAPHS + g) * 64 + c];
  }
  const float cnt = fmaxf((float)(gstart[g + 1] - gstart[g]), 1.0f);
  const float mean = s / cnt;
  const float mm = mean * ms[c];
  float var = q / cnt - 2.f * mm * mean + mm * mm;
  MM[i] = mm;
  IS[i] = rsqrtf(fmaxf(var, 0.f) + EPSN);
}

__global__ void k_norm_res(const float* __restrict__ F, const int* __restrict__ batch,
                           const float* __restrict__ MM, const float* __restrict__ IS,
                           const float* __restrict__ w, const float* __restrict__ b,
                           float* __restrict__ X, u16* __restrict__ Xb, int residual) {
  const long i4 = (long)blockIdx.x * 256 + threadIdx.x;
  const int n = (int)(i4 >> 4);
  const int c4 = (int)(i4 & 15) << 2;
  const int g = batch[n];
  float4 f = *(const float4*)(F + i4 * 4);
  float4 mm = *(const float4*)(MM + g * 64 + c4);
  float4 is = *(const float4*)(IS + g * 64 + c4);
  float4 wv = *(const float4*)(w + c4);
  float4 bv = *(const float4*)(b + c4);
  float4 y;
  y.x = fmaf(wv.x * (f.x - mm.x), is.x, bv.x);
  y.y = fmaf(wv.y * (f.y - mm.y), is.y, bv.y);
  y.z = fmaf(wv.z * (f.z - mm.z), is.z, bv.z);
  y.w = fmaf(wv.w * (f.w - mm.w), is.w, bv.w);
  float4* xp = (float4*)(X + i4 * 4);
  if (residual) {
    float4 xo = *xp;
    y.x += xo.x; y.y += xo.y; y.z += xo.z; y.w += xo.w;
  }
  *xp = y;
  union { u16 s[4]; unsigned long long ll; } pk;
  pk.s[0] = f2bf(y.x); pk.s[1] = f2bf(y.y); pk.s[2] = f2bf(y.z); pk.s[3] = f2bf(y.w);
  *(unsigned long long*)(Xb + i4 * 4) = pk.ll;
}

// ---------------- pooled MLP head (one block) ----------------
__global__ __launch_bounds__(512) void k_mlp(
    const float* __restrict__ SP, const int* __restrict__ gstart, const float* __restrict__ gf,
    const float* __restrict__ W0, const float* __restrict__ b0,
    const float* __restrict__ lw0, const float* __restrict__ lb0,
    const float* __restrict__ Wg, const float* __restrict__ bg,
    const float* __restrict__ lwg, const float* __restrict__ lbg,
    const float* __restrict__ hW, const float* __restrict__ hb,
    float* __restrict__ out) {
  __shared__ float P[16][88];
  __shared__ float Z[16][32];
  const int tid = threadIdx.x;
  for (int i = tid; i < 16 * 88; i += 512) {
    int g = i / 88, c = i - g * 88;
    float v;
    if (c < 64) {
      float s = 0.f;
      #pragma unroll
      for (int b = 0; b < NPART; ++b) s += SP[(b * N_GRAPHS + g) * 64 + c];
      float cnt = fmaxf((float)(gstart[g + 1] - gstart[g]), 1.0f);
      v = s / cnt;
    } else {
      v = gf[g * GDIM + (c - 64)];
    }
    P[g][c] = v;
  }
  __syncthreads();
  const int g = tid >> 5, c = tid & 31;
  float acc = b0[c];
  for (int k = 0; k < 88; ++k) acc = fmaf(P[g][k], W0[k * 32 + c], acc);
  float z = ln32(gelu_exact(acc), lw0[c], lb0[c]);
  for (int l = 0; l < LL; ++l) {
    Z[g][c] = z;
    __syncthreads();
    float a2 = bg[l * 32 + c];
    const float* Wl = Wg + l * 32 * 32;
    for (int k = 0; k < 32; ++k) a2 = fmaf(Z[g][k], Wl[k * 32 + c], a2);
    __syncthreads();
    z = ln32(gelu_exact(a2), lwg[l * 32 + c], lbg[l * 32 + c]) + z;
  }
  Z[g][c] = z * hW[c];
  __syncthreads();
  if (c == 0) {
    float s = 0.f;
    for (int k = 0; k < 32; ++k) s += Z[g][k];
    out[g] = s + hb[0];
  }
}

extern "C" void kernel_launch(void* const* d_in, const int* in_sizes, int n_in,
                              void* d_out, int out_size, void* d_ws, size_t ws_size,
                              hipStream_t stream) {
  const float* x   = (const float*)d_in[0];
  const int*   ei  = (const int*)d_in[1];
  const int* batch = (const int*)d_in[2];
  const float* gf  = (const float*)d_in[3];
  const float* W0  = (const float*)d_in[4];
  const float* as0 = (const float*)d_in[5];
  const float* ad0 = (const float*)d_in[6];
  const float* b0  = (const float*)d_in[7];
  const float* gw0 = (const float*)d_in[8];
  const float* gb0 = (const float*)d_in[9];
  const float* gm0 = (const float*)d_in[10];
  const float* Wg  = (const float*)d_in[11];
  const float* asg = (const float*)d_in[12];
  const float* adg = (const float*)d_in[13];
  const float* bg  = (const float*)d_in[14];
  const float* gwg = (const float*)d_in[15];
  const float* gbg = (const float*)d_in[16];
  const float* gmg = (const float*)d_in[17];
  const float* mW0 = (const float*)d_in[18];
  const float* mb0 = (const float*)d_in[19];
  const float* lw0 = (const float*)d_in[20];
  const float* lb0 = (const float*)d_in[21];
  const float* mWg = (const float*)d_in[22];
  const float* mbg = (const float*)d_in[23];
  const float* lwg = (const float*)d_in[24];
  const float* lbg = (const float*)d_in[25];
  const float* hW  = (const float*)d_in[26];
  const float* hb  = (const float*)d_in[27];
  float* out = (float*)d_out;
  const int* src = ei;
  const int* dst = ei + N_EDGES;

  char* p = (char*)d_ws;
  auto alloc = [&](size_t bytes) {
    char* r = p;
    p += (bytes + 255) & ~(size_t)255;
    return (void*)r;
  };
  float* X   = (float*)alloc((size_t)N_NODES * 64 * 4);
  float* F   = (float*)alloc((size_t)N_NODES * 64 * 4);
  u16*   Xb  = (u16*)alloc((size_t)N_NODES * 64 * 2);
  u16*   Tb  = (u16*)alloc((size_t)N_NODES * 64 * 2);
  float* ES  = (float*)alloc((size_t)N_NODES * 4 * 4);
  float* ED  = (float*)alloc((size_t)N_NODES * 4 * 4);
  int* ssrc  = (int*)alloc((size_t)N_EDGES * 4);
  int* deg   = (int*)alloc((size_t)N_NODES * 4);
  int* off   = (int*)alloc((size_t)(N_NODES + 1) * 4);
  int* cur   = (int*)alloc((size_t)N_NODES * 4);
  int* bsum  = (int*)alloc(4096);
  int* gstart = (int*)alloc((N_GRAPHS + 1) * 4);
  u16* W0s   = (u16*)alloc((size_t)W0S_ELEMS * 2);
  u16* Wgs   = (u16*)alloc((size_t)GL * WGS_ELEMS * 2);
  float* SP  = (float*)alloc(NPART * N_GRAPHS * 64 * 4);
  float* SQP = (float*)alloc(NPART * N_GRAPHS * 64 * 4);
  float* MM  = (float*)alloc(N_GRAPHS * 64 * 4);
  float* IS  = (float*)alloc(N_GRAPHS * 64 * 4);
  (void)ws_size; (void)in_sizes; (void)n_in; (void)out_size;

  const int NB = (N_NODES + 255) / 256;
  hipMemsetAsync(deg, 0, (size_t)N_NODES * 4, stream);
  k_count_part<<<2048, 256, 0, stream>>>(dst, deg);
  k_block_sums<<<NB, 256, 0, stream>>>(deg, bsum);
  k_scan_bsums<<<1, 512, 0, stream>>>(bsum, NB, off);
  k_scan_final<<<NB, 256, 0, stream>>>(deg, bsum, off, cur);
  k_scatter_part<<<2048, 256, 0, stream>>>(src, dst, cur, ssrc);
  k_graph_starts<<<1, 32, 0, stream>>>(batch, gstart);
  k_prep_w<<<(W0S_ELEMS + GL * WGS_ELEMS + 255) / 256, 256, 0, stream>>>(W0, Wg, W0s, Wgs);

  const int GG = (N_NODES / 16 + 3) / 4;
  for (int l = 0; l < 1 + GL; ++l) {
    const float* asl = (l == 0) ? as0 : (asg + (size_t)(l - 1) * 64);
    const float* adl = (l == 0) ? ad0 : (adg + (size_t)(l - 1) * 64);
    const float* bl  = (l == 0) ? b0  : (bg  + (size_t)(l - 1) * 64);
    const float* gwl = (l == 0) ? gw0 : (gwg + (size_t)(l - 1) * 64);
    const float* gbl = (l == 0) ? gb0 : (gbg + (size_t)(l - 1) * 64);
    const float* gml = (l == 0) ? gm0 : (gmg + (size_t)(l - 1) * 64);
    if (l == 0)
      k_gemm_mfma<9, true><<<GG, 256, 0, stream>>>(x, W0s, asl, adl, Tb, ES, ED);
    else
      k_gemm_mfma<2, false><<<GG, 256, 0, stream>>>(Xb, Wgs + (size_t)(l - 1) * WGS_ELEMS,
                                                    asl, adl, Tb, ES, ED);
    k_edge_agg<<<N_NODES / 4, 256, 0, stream>>>(Tb, ES, ED, off, ssrc, bl, F);
    k_graph_moments<<<dim3(N_GRAPHS, NPART), 256, 0, stream>>>(F, gstart, SP, SQP);
    k_graph_stats<<<1, 1024, 0, stream>>>(SP, SQP, gstart, gml, MM, IS);
    k_norm_res<<<(N_NODES * 64) / 1024, 256, 0, stream>>>(F, batch, MM, IS, gwl, gbl, X, Xb, l > 0);
  }

  k_graph_moments<<<dim3(N_GRAPHS, NPART), 256, 0, stream>>>(X, gstart, SP, SQP);
  k_mlp<<<1, 512, 0, stream>>>(SP, gstart, gf, mW0, mb0, lw0, lb0,
                               mWg, mbg, lwg, lbg, hW, hb, out);
}